// Round 8
// baseline (162.848 us; speedup 1.0000x reference)
//
#include <hip/hip_runtime.h>
#include <math.h>
#include <stdint.h>

#define B_ 8
#define L_ 2048
#define D_ 256
#define NEG_INF_V (-1e10f)

typedef __bf16 bf16x8 __attribute__((ext_vector_type(8)));
typedef float f32x4 __attribute__((ext_vector_type(4)));

#define MFMA16(a, b, c) __builtin_amdgcn_mfma_f32_16x16x32_bf16((a), (b), (c), 0, 0, 0)

// Fragment-major (FM) layout for a [rows x 256] bf16 matrix:
// granule index = ((G * 8 + kb) * 64 + q * 16 + m) ; granule = 16B = 8 bf16
// holds M[G*16 + m][kb*32 + q*8 .. +8).  G = absolute row/16.

// ---------- K0: src fp32 -> bf16 FM + row sumsq; W -> WFM; init Sarr/counter ----------
__global__ __launch_bounds__(256) void convert_kernel(
    const float* __restrict__ x, const float* __restrict__ W,
    __bf16* __restrict__ srcFM, __bf16* __restrict__ WFM,
    float* __restrict__ src_sq,
    float* __restrict__ Sarr, unsigned int* __restrict__ counter) {
    int tid = threadIdx.x;
    int blk = blockIdx.x;
    if (blk < 1024) {
        int g = blk;  // row-group (16 rows)
        __shared__ __align__(16) __bf16 sFM[512 * 8];
        __shared__ float sSQ[16];
        int kb = (tid & 31) >> 2, qq = tid & 3;
        #pragma unroll
        for (int pass = 0; pass < 2; ++pass) {
            int m = pass * 8 + (tid >> 5);
            const float* p = x + ((size_t)g * 16 + m) * D_ + (tid & 31) * 8;
            float4 v0 = *(const float4*)p;
            float4 v1 = *(const float4*)(p + 4);
            float ss = v0.x * v0.x + v0.y * v0.y + v0.z * v0.z + v0.w * v0.w +
                       v1.x * v1.x + v1.y * v1.y + v1.z * v1.z + v1.w * v1.w;
            #pragma unroll
            for (int o = 16; o > 0; o >>= 1) ss += __shfl_xor(ss, o, 64);
            if ((tid & 31) == 0) sSQ[m] = ss;
            union { __bf16 o[8]; bf16x8 v; } cv;
            cv.o[0] = (__bf16)v0.x; cv.o[1] = (__bf16)v0.y;
            cv.o[2] = (__bf16)v0.z; cv.o[3] = (__bf16)v0.w;
            cv.o[4] = (__bf16)v1.x; cv.o[5] = (__bf16)v1.y;
            cv.o[6] = (__bf16)v1.z; cv.o[7] = (__bf16)v1.w;
            *(bf16x8*)(sFM + (m * 32 + kb * 4 + qq) * 8) = cv.v;
        }
        __syncthreads();
        int G0 = tid * 2;
        int kb0 = G0 >> 6, q0 = (G0 >> 4) & 3, m0 = G0 & 15;
        bf16x8 a = *(const bf16x8*)(sFM + (m0 * 32 + kb0 * 4 + q0) * 8);
        bf16x8 bgr = *(const bf16x8*)(sFM + ((m0 + 1) * 32 + kb0 * 4 + q0) * 8);
        *(bf16x8*)(srcFM + ((size_t)g * 512 + G0) * 8) = a;
        *(bf16x8*)(srcFM + ((size_t)g * 512 + G0 + 1) * 8) = bgr;
        if (tid < 16) src_sq[g * 16 + tid] = sSQ[tid];
    } else {
        if (blk == 1024) {  // zero cross-kernel accumulators (used by flash_fused)
            if (tid < 24) Sarr[tid] = 0.f;
            if (tid == 24) *counter = 0u;
        }
        // W packed as FM of W^T (rows = output col n, cols = d)
        int idx = (blk - 1024) * 256 + tid;
        int m = idx & 15, q = (idx >> 4) & 3, kb = (idx >> 6) & 7, gn = idx >> 9;
        union { __bf16 o[8]; bf16x8 v; } cv;
        #pragma unroll
        for (int j = 0; j < 8; ++j)
            cv.o[j] = (__bf16)W[(size_t)(kb * 32 + q * 8 + j) * D_ + gn * 16 + m];
        *(bf16x8*)(WFM + (size_t)idx * 8) = cv.v;
    }
}

// ---------- K1: fused pred conversion + predW GEMM (R5-proven) ----------
__global__ __launch_bounds__(256, 4) void predconv_predw(
    const float* __restrict__ y, const __bf16* __restrict__ WFM,
    const float* __restrict__ pred_mask,
    __bf16* __restrict__ predFM, float* __restrict__ pred_sq,
    __bf16* __restrict__ pwFM) {
    __shared__ __align__(16) __bf16 sP[64 * 264];
    __shared__ int flag;
    int tid = threadIdx.x, lane = tid & 63, wid = tid >> 6;
    int id = blockIdx.x;
    int b = id & 7, t8 = id >> 3;
    int g1 = b * 32 + t8;
    size_t R0 = (size_t)g1 * 64;
    if (tid == 0) flag = 0;
    __syncthreads();
    if (tid < 64) { if (pred_mask[R0 + tid] != 0.f) atomicOr(&flag, 1); }

    int q = lane >> 4, m = lane & 15;
    float ss = 0.f;
    const float* yb = y + (R0 + wid * 16 + m) * D_ + q * 8;
    __bf16* pfb = predFM + (((size_t)(g1 * 4 + wid) * 8) * 64 + lane) * 8;
    #pragma unroll
    for (int kb = 0; kb < 8; ++kb) {
        float4 v0 = *(const float4*)(yb + kb * 32);
        float4 v1 = *(const float4*)(yb + kb * 32 + 4);
        ss += v0.x * v0.x + v0.y * v0.y + v0.z * v0.z + v0.w * v0.w +
              v1.x * v1.x + v1.y * v1.y + v1.z * v1.z + v1.w * v1.w;
        union { __bf16 o[8]; bf16x8 v; } cv;
        cv.o[0] = (__bf16)v0.x; cv.o[1] = (__bf16)v0.y;
        cv.o[2] = (__bf16)v0.z; cv.o[3] = (__bf16)v0.w;
        cv.o[4] = (__bf16)v1.x; cv.o[5] = (__bf16)v1.y;
        cv.o[6] = (__bf16)v1.z; cv.o[7] = (__bf16)v1.w;
        *(bf16x8*)(sP + ((wid * 8 + kb) * 64 + lane) * 8) = cv.v;
        *(bf16x8*)(pfb + (size_t)kb * 512) = cv.v;
    }
    ss += __shfl_xor(ss, 16, 64);
    ss += __shfl_xor(ss, 32, 64);
    if (q == 0) pred_sq[R0 + wid * 16 + m] = ss;
    __syncthreads();
    if (!flag) return;

    int wp = wid >> 1, wn = wid & 1;
    f32x4 acc[2][8] = {};
    const __bf16* bB = WFM + ((size_t)(wn * 8) * 8 * 64 + lane) * 8;
    #pragma unroll
    for (int kb = 0; kb < 8; ++kb) {
        bf16x8 fA[2];
        #pragma unroll
        for (int a = 0; a < 2; ++a)
            fA[a] = *(const bf16x8*)(sP + (((wp * 2 + a) * 8 + kb) * 64 + lane) * 8);
        #pragma unroll
        for (int h = 0; h < 2; ++h) {
            bf16x8 fB[4];
            #pragma unroll
            for (int t = 0; t < 4; ++t)
                fB[t] = *(const bf16x8*)(bB + ((size_t)((h * 4 + t) * 8 + kb) * 64) * 8);
            #pragma unroll
            for (int a = 0; a < 2; ++a)
                #pragma unroll
                for (int t = 0; t < 4; ++t)
                    acc[a][h * 4 + t] = MFMA16(fA[a], fB[t], acc[a][h * 4 + t]);
        }
    }
    int cn = lane & 15;
    #pragma unroll
    for (int h = 0; h < 2; ++h) {
        __syncthreads();
        if (wn == h) {
            #pragma unroll
            for (int a = 0; a < 2; ++a)
                #pragma unroll
                for (int t = 0; t < 8; ++t)
                    #pragma unroll
                    for (int r = 0; r < 4; ++r)
                        sP[(wp * 32 + a * 16 + q * 4 + r) * 136 + t * 16 + cn] =
                            (__bf16)acc[a][t][r];
        }
        __syncthreads();
        #pragma unroll
        for (int i = 0; i < 4; ++i) {
            int idx = i * 256 + tid;
            int G = idx >> 8, kbl = (idx >> 6) & 3, qq = (idx >> 4) & 3, mm = idx & 15;
            bf16x8 v = *(const bf16x8*)(sP + (G * 16 + mm) * 136 + kbl * 32 + qq * 8);
            *(bf16x8*)(pwFM +
                       (((size_t)(g1 * 4 + G) * 8 + h * 4 + kbl) * 64 + qq * 16 + mm) * 8) = v;
        }
    }
}

// ---------- K2: flash-style fused: full-row online softmax, no partials ----------
// 512 blocks = (b = blk&7, pg = blk>>3). Block owns 32 p-rows x all 2048 s.
// 4 waves: rg = wid>>1 (rows rg*16..+16), sp = wid&1 (even/odd strips).
// Wave keeps pred/pw panels resident in regs (fP[8], fW[8]); loops 16
// strip-pairs: stage 64KB src pair -> per-strip aG/aT MFMA -> per-strip
// row-reduce + online (m,l,w) merge in registers. Strip-valid bitmask
// precomputed once; masked-tail iterations skipped (uniform branch);
// T-GEMM skipped when block has no valid p. NEG_INF semantics identical
// to the strip kernel (pm==0 -> tv=0 uniform row; masked s -> -1e10).
// Tail: sp-pair merge via LDS, sv=w/l, 3 atomics + counter==511 finalize.
__global__ __launch_bounds__(256, 2) void flash_fused(
    const __bf16* __restrict__ srcFM, const __bf16* __restrict__ predFM,
    const __bf16* __restrict__ pwFM,
    const float* __restrict__ x_mask, const float* __restrict__ y_mask,
    const float* __restrict__ src_sq, const float* __restrict__ pred_sq,
    float* __restrict__ Sarr, unsigned int* __restrict__ counter,
    float* __restrict__ out) {
    __shared__ __align__(16) __bf16 sS[2 * 64 * 256];  // 64KB: strips 2t, 2t+1
    __shared__ float sSM2[128], sSSQ2[128];
    __shared__ float sPM[32], sPSQ[32];
    __shared__ int flgI[34];  // [0..31] strip anyValidS, [32] anyVP, [33] anyIP
    __shared__ int isLast;
    int tid = threadIdx.x, lane = tid & 63, wid = tid >> 6;
    int rg = wid >> 1, sp = wid & 1;
    int blk = blockIdx.x;
    int b = blk & 7, pg = blk >> 3;
    int p0 = pg * 32;

    // ---- precompute flags + row data ----
    if (tid < 34) flgI[tid] = 0;
    __syncthreads();
    if (tid < 32) {
        float v = y_mask[b * L_ + p0 + tid];
        sPM[tid] = v;
        sPSQ[tid] = pred_sq[b * L_ + p0 + tid];
        atomicOr(&flgI[(v != 0.f) ? 32 : 33], 1);
    }
    {   // strip-valid flags over all 2048 s (8 per thread)
        const float* xm = x_mask + b * L_;
        int s0 = tid * 8;
        int any = 0;
        #pragma unroll
        for (int j = 0; j < 8; ++j) any |= (xm[s0 + j] != 0.f) ? 1 : 0;
        if (any) atomicOr(&flgI[s0 >> 6], 1);
    }
    __syncthreads();
    unsigned int vmask = 0;
    for (int s = 0; s < 32; ++s) vmask |= (flgI[s] ? 1u : 0u) << s;
    const bool anyVP = flgI[32] != 0, anyIP = flgI[33] != 0;

    // resident pred/pw panels for this wave's 16 rows
    int Gp = b * 128 + pg * 2 + rg;
    bf16x8 fP[8], fW[8];
    {
        const __bf16* bP = predFM + (size_t)Gp * 4096 + lane * 8;
        const __bf16* bW = pwFM + (size_t)Gp * 4096 + lane * 8;
        #pragma unroll
        for (int kb = 0; kb < 8; ++kb) {
            fP[kb] = *(const bf16x8*)(bP + kb * 512);
            fW[kb] = *(const bf16x8*)(bW + kb * 512);
        }
    }
    int q = lane >> 4, cn = lane & 15;
    float pm4[4], psq4[4];
    #pragma unroll
    for (int r = 0; r < 4; ++r) {
        pm4[r] = sPM[rg * 16 + q * 4 + r];
        psq4[r] = sPSQ[rg * 16 + q * 4 + r];
    }
    float m4[4] = {-1e30f, -1e30f, -1e30f, -1e30f};
    float l4[4] = {0.f, 0.f, 0.f, 0.f};
    float w4[4] = {0.f, 0.f, 0.f, 0.f};

    bool seen = false;
    for (int t = 0; t < 16; ++t) {
        bool v0 = (vmask >> (2 * t)) & 1, v1 = (vmask >> (2 * t + 1)) & 1;
        // uniform skip: both strips masked, no pm==0 rows, and a valid strip
        // already processed -> contribution is exactly exp(-1e10 - m) = 0.
        if (!v0 && !v1 && !anyIP && seen) continue;
        {   // stage strips 2t, 2t+1 (64KB contiguous) + their masks/sumsq
            const __bf16* g = srcFM + ((size_t)(b * 128 + t * 8)) * 4096;
            #pragma unroll
            for (int i = 0; i < 16; ++i) {
                size_t off = (size_t)i * 2048 + tid * 8;
                *(bf16x8*)(sS + off) = *(const bf16x8*)(g + off);
            }
            if (tid < 128) {
                int ssp = tid >> 6, si = tid & 63;
                int sidx = b * L_ + (2 * t + ssp) * 64 + si;
                sSM2[tid] = x_mask[sidx];
                sSSQ2[tid] = src_sq[sidx];
            }
        }
        __syncthreads();
        bool vs = sp ? v1 : v0;
        bool doTw = anyVP && vs;
        const __bf16* bS = sS + sp * 16384 + lane * 8;
        f32x4 aG[4] = {};
        f32x4 aT[4] = {};
        if (doTw) {
            #pragma unroll
            for (int kb = 0; kb < 8; ++kb) {
                bf16x8 fB[4];
                #pragma unroll
                for (int ct = 0; ct < 4; ++ct)
                    fB[ct] = *(const bf16x8*)(bS + (ct * 8 + kb) * 512);
                #pragma unroll
                for (int ct = 0; ct < 4; ++ct) {
                    aG[ct] = MFMA16(fP[kb], fB[ct], aG[ct]);
                    aT[ct] = MFMA16(fW[kb], fB[ct], aT[ct]);
                }
            }
        } else {
            #pragma unroll
            for (int kb = 0; kb < 8; ++kb) {
                bf16x8 fB[4];
                #pragma unroll
                for (int ct = 0; ct < 4; ++ct)
                    fB[ct] = *(const bf16x8*)(bS + (ct * 8 + kb) * 512);
                #pragma unroll
                for (int ct = 0; ct < 4; ++ct)
                    aG[ct] = MFMA16(fP[kb], fB[ct], aG[ct]);
            }
        }
        float smv[4], sqv[4];
        #pragma unroll
        for (int ct = 0; ct < 4; ++ct) {
            smv[ct] = sSM2[sp * 64 + ct * 16 + cn];
            sqv[ct] = sSSQ2[sp * 64 + ct * 16 + cn];
        }
        #pragma unroll
        for (int r = 0; r < 4; ++r) {
            float pm = pm4[r], psq = psq4[r];
            float tv[4], cst[4];
            float tm = -1e30f;
            #pragma unroll
            for (int ct = 0; ct < 4; ++ct) {
                cst[ct] = __builtin_amdgcn_sqrtf(
                    fmaxf(psq + sqv[ct] - 2.f * aG[ct][r], 0.f));
                float tt = doTw ? aT[ct][r] : NEG_INF_V;
                // pm==0: uniform row (tv=0 -> e=1 everywhere)
                tv[ct] = (pm == 0.f) ? 0.f : (smv[ct] != 0.f ? tt : NEG_INF_V);
                tm = fmaxf(tm, tv[ct]);
            }
            #pragma unroll
            for (int o = 8; o > 0; o >>= 1) tm = fmaxf(tm, __shfl_xor(tm, o, 16));
            float le = 0.f, we = 0.f;
            #pragma unroll
            for (int ct = 0; ct < 4; ++ct) {
                float e = __expf(tv[ct] - tm);
                le += e;
                we = fmaf(e, cst[ct], we);
            }
            #pragma unroll
            for (int o = 8; o > 0; o >>= 1) {
                le += __shfl_xor(le, o, 16);
                we += __shfl_xor(we, o, 16);
            }
            // online merge into row state
            float M = fmaxf(m4[r], tm);
            float e1 = __expf(m4[r] - M), e2 = __expf(tm - M);
            l4[r] = l4[r] * e1 + le * e2;
            w4[r] = w4[r] * e1 + we * e2;
            m4[r] = M;
        }
        seen = seen || v0 || v1;
        __syncthreads();  // before next iteration overwrites sS/sSM2
    }

    // ---- tail: merge sp pairs, reduce block, atomic into Sarr ----
    __syncthreads();
    float* mrg = (float*)sS;  // sS dead; 64 rows x 3 floats
    if (cn == 0) {
        #pragma unroll
        for (int r = 0; r < 4; ++r) {
            int row = wid * 16 + q * 4 + r;
            mrg[row * 3 + 0] = m4[r];
            mrg[row * 3 + 1] = l4[r];
            mrg[row * 3 + 2] = w4[r];
        }
    }
    __syncthreads();
    float sv = 0.f, n1 = 0.f, n2 = 0.f;
    if (tid < 32) {
        int rgi = tid >> 4, rr = tid & 15;
        int rowA = (rgi * 2 + 0) * 16 + rr, rowB = (rgi * 2 + 1) * 16 + rr;
        float ma = mrg[rowA * 3], la = mrg[rowA * 3 + 1], wa = mrg[rowA * 3 + 2];
        float mb = mrg[rowB * 3], lb = mrg[rowB * 3 + 1], wb = mrg[rowB * 3 + 2];
        float M = fmaxf(ma, mb);
        float e1 = __expf(ma - M), e2 = __expf(mb - M);
        float l = la * e1 + lb * e2;
        float w = wa * e1 + wb * e2;
        sv = w / l;
        n1 = y_mask[b * L_ + p0 + tid];
        n2 = x_mask[b * L_ + p0 + tid];
    }
    #pragma unroll
    for (int o = 16; o > 0; o >>= 1) {
        sv += __shfl_xor(sv, o, 32);
        n1 += __shfl_xor(n1, o, 32);
        n2 += __shfl_xor(n2, o, 32);
    }
    if (tid == 0) {
        atomicAdd(&Sarr[b], sv);
        atomicAdd(&Sarr[8 + b], n1);
        atomicAdd(&Sarr[16 + b], n2);
        __threadfence();
        isLast = (atomicAdd(counter, 1u) == 511u) ? 1 : 0;
    }
    __syncthreads();
    if (isLast) {
        __shared__ float fb[24];
        if (tid < 24) fb[tid] = atomicAdd(&Sarr[tid], 0.f);  // coherent read
        __syncthreads();
        if (tid == 0) {
            float ss = 0.f, si = 0.f;
            for (int bb = 0; bb < B_; bb++) {
                ss += fb[bb];
                si += 1.0f / (fb[8 + bb] * fb[16 + bb]);
            }
            out[0] = ss * si / (float)(B_ * B_);  // LAMBDA_W = 1.0
        }
    }
}

extern "C" void kernel_launch(void* const* d_in, const int* in_sizes, int n_in,
                              void* d_out, int out_size, void* d_ws, size_t ws_size,
                              hipStream_t stream) {
    const float* h_x = (const float*)d_in[0];     // src
    const float* h_y = (const float*)d_in[1];     // pred
    const float* x_mask = (const float*)d_in[2];  // src_mask
    const float* y_mask = (const float*)d_in[3];  // pred_mask
    const float* W = (const float*)d_in[4];

    char* w8 = (char*)d_ws;
    const size_t BLD2 = (size_t)B_ * L_ * D_ * 2;  // 8 MB
    __bf16* srcFM = (__bf16*)w8;
    __bf16* predFM = (__bf16*)(w8 + BLD2);
    __bf16* pwFM = (__bf16*)(w8 + 2 * BLD2);
    __bf16* WFM = (__bf16*)(w8 + 3 * BLD2);                   // 128 KB
    float* src_sq = (float*)(w8 + 3 * BLD2 + (1 << 17));      // 64 KB
    float* pred_sq = (float*)(w8 + 3 * BLD2 + (1 << 17) + (1 << 16));
    char* ctrl = w8 + 3 * BLD2 + (1 << 17) + (1 << 17);
    float* Sarr = (float*)ctrl;                               // 24 floats
    unsigned int* counter = (unsigned int*)(ctrl + 128);

    convert_kernel<<<1056, 256, 0, stream>>>(h_x, W, srcFM, WFM, src_sq,
                                             Sarr, counter);
    predconv_predw<<<256, 256, 0, stream>>>(h_y, WFM, y_mask, predFM, pred_sq,
                                            pwFM);
    flash_fused<<<512, 256, 0, stream>>>(
        srcFM, predFM, pwFM, x_mask, y_mask, src_sq, pred_sq,
        Sarr, counter, (float*)d_out);
}

// Round 9
// 135.688 us; speedup vs baseline: 1.2002x; 1.2002x over previous
//
#include <hip/hip_runtime.h>
#include <math.h>
#include <stdint.h>

#define B_ 8
#define L_ 2048
#define D_ 256
#define NEG_INF_V (-1e10f)
#define NSTRIP 32

typedef __bf16 bf16x8 __attribute__((ext_vector_type(8)));
typedef float f32x4 __attribute__((ext_vector_type(4)));

#define MFMA16(a, b, c) __builtin_amdgcn_mfma_f32_16x16x32_bf16((a), (b), (c), 0, 0, 0)

// Fragment-major (FM) layout for a [rows x 256] bf16 matrix:
// granule index = ((G * 8 + kb) * 64 + q * 16 + m) ; granule = 16B = 8 bf16
// holds M[G*16 + m][kb*32 + q*8 .. +8).  G = absolute row/16.
// A wave (lane = q*16+m) loads frag (G_tile, kb) as one coalesced 1KB segment.

// ---------- K0: fp32 -> bf16 FM transform (coalesced) + row sumsq + W FM ----------
__global__ __launch_bounds__(256) void convert_kernel(
    const float* __restrict__ x, const float* __restrict__ y,
    const float* __restrict__ W,
    __bf16* __restrict__ srcFM, __bf16* __restrict__ predFM,
    __bf16* __restrict__ WFM,
    float* __restrict__ src_sq, float* __restrict__ pred_sq) {
    int tid = threadIdx.x;
    int blk = blockIdx.x;
    if (blk < 2048) {
        const float* in = (blk < 1024) ? x : y;
        __bf16* out = (blk < 1024) ? srcFM : predFM;
        float* sqout = (blk < 1024) ? src_sq : pred_sq;
        int g = blk & 1023;  // row-group (16 rows)
        __shared__ __align__(16) __bf16 sFM[512 * 8];
        __shared__ float sSQ[16];
        int kb = (tid & 31) >> 2, qq = tid & 3;
        #pragma unroll
        for (int pass = 0; pass < 2; ++pass) {
            int m = pass * 8 + (tid >> 5);
            const float* p = in + ((size_t)g * 16 + m) * D_ + (tid & 31) * 8;
            float4 v0 = *(const float4*)p;
            float4 v1 = *(const float4*)(p + 4);
            float ss = v0.x * v0.x + v0.y * v0.y + v0.z * v0.z + v0.w * v0.w +
                       v1.x * v1.x + v1.y * v1.y + v1.z * v1.z + v1.w * v1.w;
            #pragma unroll
            for (int o = 16; o > 0; o >>= 1) ss += __shfl_xor(ss, o, 64);
            if ((tid & 31) == 0) sSQ[m] = ss;
            union { __bf16 o[8]; bf16x8 v; } cv;
            cv.o[0] = (__bf16)v0.x; cv.o[1] = (__bf16)v0.y;
            cv.o[2] = (__bf16)v0.z; cv.o[3] = (__bf16)v0.w;
            cv.o[4] = (__bf16)v1.x; cv.o[5] = (__bf16)v1.y;
            cv.o[6] = (__bf16)v1.z; cv.o[7] = (__bf16)v1.w;
            *(bf16x8*)(sFM + (m * 32 + kb * 4 + qq) * 8) = cv.v;
        }
        __syncthreads();
        int G0 = tid * 2;
        int kb0 = G0 >> 6, q0 = (G0 >> 4) & 3, m0 = G0 & 15;
        bf16x8 a = *(const bf16x8*)(sFM + (m0 * 32 + kb0 * 4 + q0) * 8);
        bf16x8 bgr = *(const bf16x8*)(sFM + ((m0 + 1) * 32 + kb0 * 4 + q0) * 8);
        *(bf16x8*)(out + ((size_t)g * 512 + G0) * 8) = a;
        *(bf16x8*)(out + ((size_t)g * 512 + G0 + 1) * 8) = bgr;
        if (tid < 16) sqout[g * 16 + tid] = sSQ[tid];
    } else {
        int idx = (blk - 2048) * 256 + tid;
        int m = idx & 15, q = (idx >> 4) & 3, kb = (idx >> 6) & 7, gn = idx >> 9;
        union { __bf16 o[8]; bf16x8 v; } cv;
        #pragma unroll
        for (int j = 0; j < 8; ++j)
            cv.o[j] = (__bf16)W[(size_t)(kb * 32 + q * 8 + j) * D_ + gn * 16 + m];
        *(bf16x8*)(WFM + (size_t)idx * 8) = cv.v;
    }
}

// ---------- K1: predW = pred x W, FM in / FM out (XCD-swizzled) ----------
__global__ __launch_bounds__(256, 2) void predw_mfma(
    const __bf16* __restrict__ predFM, const __bf16* __restrict__ WFM,
    const float* __restrict__ pred_mask, __bf16* __restrict__ pwFM) {
    __shared__ __align__(16) __bf16 sT[128 * 136];
    __shared__ int flag;
    int tid = threadIdx.x, lane = tid & 63, wid = tid >> 6;
    int wp = wid >> 1, wn = wid & 1;
    int id = blockIdx.x;
    int m0 = (((id >> 3) & 15) + (id & 7) * 16) * 128;
    int n0 = (id >> 7) * 128;
    if (tid == 0) flag = 0;
    __syncthreads();
    if (tid < 128) { if (pred_mask[m0 + tid] != 0.f) atomicOr(&flag, 1); }
    __syncthreads();
    if (!flag) return;

    const __bf16* bA = predFM + (size_t)(m0 / 16 + wp * 4) * 4096 + lane * 8;
    const __bf16* bB = WFM + (size_t)(n0 / 16 + wn * 4) * 4096 + lane * 8;
    f32x4 acc[4][4] = {};
    #pragma unroll
    for (int kb = 0; kb < 8; ++kb) {
        bf16x8 fA[4], fB[4];
        #pragma unroll
        for (int t = 0; t < 4; ++t) {
            fA[t] = *(const bf16x8*)(bA + (t * 8 + kb) * 512);
            fB[t] = *(const bf16x8*)(bB + (t * 8 + kb) * 512);
        }
        #pragma unroll
        for (int pt = 0; pt < 4; ++pt)
            #pragma unroll
            for (int st = 0; st < 4; ++st)
                acc[pt][st] = MFMA16(fA[pt], fB[st], acc[pt][st]);
    }
    int q = lane >> 4, cn = lane & 15;
    #pragma unroll
    for (int pt = 0; pt < 4; ++pt)
        #pragma unroll
        for (int st = 0; st < 4; ++st)
            #pragma unroll
            for (int r = 0; r < 4; ++r)
                sT[(wp * 64 + pt * 16 + q * 4 + r) * 136 + wn * 64 + st * 16 + cn] =
                    (__bf16)acc[pt][st][r];
    __syncthreads();
    #pragma unroll
    for (int i = 0; i < 8; ++i) {
        int idx = i * 256 + tid;
        int gl = idx >> 8, kbl = (idx >> 6) & 3, qq = (idx >> 4) & 3, mm = idx & 15;
        bf16x8 v = *(const bf16x8*)(sT + (gl * 16 + mm) * 136 + kbl * 32 + qq * 8);
        *(bf16x8*)(pwFM +
                   (((size_t)(m0 / 16 + gl) * 8 + n0 / 32 + kbl) * 64 + qq * 16 + mm) * 8) = v;
    }
}

// ---------- K2: fused T/G MFMA, 128p x 64s tiles, register-resident panels ----------
// R2-champion geometry (256 thr, 4 waves, src strip in LDS). CHANGE vs R2:
// the wave's pred/pw panels (16 x bf16x8 = 64 VGPR) are hoisted OUT of the
// K-loop into registers -- all 32 L2 loads issue as one independent burst
// (single amortized latency) instead of 4 dependent loads per kb-iter
// (R2's VGPR_Count=60 proved the compiler never pipelined them). K-loop is
// then pure ds_read_b128 + MFMA. launch_bounds(256,3): VGPR cap 170
// (est ~155); LDS 34.8KB -> 4 blocks/CU by LDS, 3 by VGPR; measured R2
// occupancy was ~10.6 waves/CU so nominal 12 loses nothing.
// grid 4096: id = b + 8*px + 128*syb  (id&7 locks batch to XCD)
__global__ __launch_bounds__(256, 3) void fused_mfma(
    const __bf16* __restrict__ srcFM, const __bf16* __restrict__ predFM,
    const __bf16* __restrict__ pwFM,
    const float* __restrict__ src_mask, const float* __restrict__ pred_mask,
    const float* __restrict__ src_sq, const float* __restrict__ pred_sq,
    float* __restrict__ m_part, float* __restrict__ l_part,
    float* __restrict__ w_part, float* __restrict__ Sarr,
    unsigned int* __restrict__ counter) {
    __shared__ __align__(16) __bf16 sS[64 * 256];  // 32KB src strip (4 G-tiles)
    __shared__ float sPM[128], sPSQ[128], sSM[64], sSSQ[64];
    __shared__ int flg[4];  // 0 anyValidP, 1 anyInvalidP, 2 anyValidS, 3 anyInvalidS
    int tid = threadIdx.x, lane = tid & 63, wid = tid >> 6;  // wid = wp 0..3
    int id = blockIdx.x;
    int b = id & 7, px = (id >> 3) & 15, syb = id >> 7;  // syb 0..31
    int p0 = px * 128, s0 = syb * 64;

    if (id == 0) {  // init cross-kernel accumulators for combine (runs after us)
        if (tid == 0) *counter = 0u;
        if (tid < 24) Sarr[tid] = 0.f;
    }
    if (tid < 4) flg[tid] = 0;
    __syncthreads();
    if (tid < 128) {
        float v = pred_mask[b * L_ + p0 + tid];
        sPM[tid] = v;
        sPSQ[tid] = pred_sq[b * L_ + p0 + tid];
        atomicOr(&flg[(v != 0.f) ? 0 : 1], 1);
    } else if (tid < 192) {
        int t = tid - 128;
        float v = src_mask[b * L_ + s0 + t];
        sSM[t] = v;
        sSSQ[t] = src_sq[b * L_ + s0 + t];
        atomicOr(&flg[(v != 0.f) ? 2 : 3], 1);
    }
    // stage src strip: contiguous 32KB, coalesced 1KB/wave-instruction.
    {
        const __bf16* g = srcFM + ((size_t)(b * 128 + syb * 4)) * 4096;
        #pragma unroll
        for (int i = 0; i < 8; ++i) {
            size_t off = (size_t)i * 2048 + tid * 8;
            *(bf16x8*)(sS + off) = *(const bf16x8*)(g + off);
        }
    }
    __syncthreads();
    const bool anyVP = flg[0] != 0, anyIP = flg[1] != 0, anyVS = flg[2] != 0;
    const bool doT = anyVP && anyVS;
    const bool doG = anyVS || anyIP;
    if (!doG) {
        // all 64 s masked & all p valid: strip is zero-weighted vs any real strip
        if (tid < 128) {
            size_t o = (size_t)syb * (B_ * L_) + b * L_ + p0 + tid;
            m_part[o] = NEG_INF_V; l_part[o] = 64.f; w_part[o] = 0.f;
        }
        return;
    }

    const __bf16* bP = predFM + ((size_t)(b * 128 + px * 8 + wid * 2)) * 4096 + lane * 8;
    const __bf16* bW = pwFM + ((size_t)(b * 128 + px * 8 + wid * 2)) * 4096 + lane * 8;
    const __bf16* bS = sS + lane * 8;

    f32x4 aG[2][4] = {};
    f32x4 aT[2][4] = {};
    if (doT) {
        // hoist both panels: 32 independent L2 loads, one amortized latency
        bf16x8 hP[2][8], hW[2][8];
        #pragma unroll
        for (int m = 0; m < 2; ++m)
            #pragma unroll
            for (int kb = 0; kb < 8; ++kb) {
                hP[m][kb] = *(const bf16x8*)(bP + (m * 8 + kb) * 512);
                hW[m][kb] = *(const bf16x8*)(bW + (m * 8 + kb) * 512);
            }
        #pragma unroll
        for (int kb = 0; kb < 8; ++kb) {
            bf16x8 fB[4];
            #pragma unroll
            for (int t = 0; t < 4; ++t)
                fB[t] = *(const bf16x8*)(bS + (t * 8 + kb) * 512);
            #pragma unroll
            for (int m = 0; m < 2; ++m)
                #pragma unroll
                for (int t = 0; t < 4; ++t) {
                    aG[m][t] = MFMA16(hP[m][kb], fB[t], aG[m][t]);
                    aT[m][t] = MFMA16(hW[m][kb], fB[t], aT[m][t]);
                }
        }
    } else {
        // G-only: hoist pred panel only (16 loads)
        bf16x8 hP[2][8];
        #pragma unroll
        for (int m = 0; m < 2; ++m)
            #pragma unroll
            for (int kb = 0; kb < 8; ++kb)
                hP[m][kb] = *(const bf16x8*)(bP + (m * 8 + kb) * 512);
        #pragma unroll
        for (int kb = 0; kb < 8; ++kb) {
            bf16x8 fB[4];
            #pragma unroll
            for (int t = 0; t < 4; ++t)
                fB[t] = *(const bf16x8*)(bS + (t * 8 + kb) * 512);
            #pragma unroll
            for (int m = 0; m < 2; ++m)
                #pragma unroll
                for (int t = 0; t < 4; ++t)
                    aG[m][t] = MFMA16(hP[m][kb], fB[t], aG[m][t]);
        }
    }

    // epilogue: element (row = wid*32 + m*16 + q*4 + r, col = t*16 + cn)
    int q = lane >> 4, cn = lane & 15;
    float smv[4], sqv[4];
    #pragma unroll
    for (int t = 0; t < 4; ++t) {
        smv[t] = sSM[t * 16 + cn];
        sqv[t] = sSSQ[t * 16 + cn];
    }
    #pragma unroll
    for (int m = 0; m < 2; ++m) {
        int rbase = wid * 32 + m * 16 + q * 4;
        #pragma unroll
        for (int r = 0; r < 4; ++r) {
            float pm = sPM[rbase + r], psq = sPSQ[rbase + r];
            float tv[4], cst[4];
            float tm = -1e30f;
            #pragma unroll
            for (int t = 0; t < 4; ++t) {
                cst[t] = __builtin_amdgcn_sqrtf(
                    fmaxf(psq + sqv[t] - 2.f * aG[m][t][r], 0.f));
                float tt = doT ? aT[m][t][r] : NEG_INF_V;
                // pm==0: uniform row (tv=0 everywhere -> e=1, l=64, w=sum cost)
                tv[t] = (pm == 0.f) ? 0.f : (smv[t] != 0.f ? tt : NEG_INF_V);
                tm = fmaxf(tm, tv[t]);
            }
            #pragma unroll
            for (int o = 8; o > 0; o >>= 1) tm = fmaxf(tm, __shfl_xor(tm, o, 16));
            float l = 0.f, w = 0.f;
            #pragma unroll
            for (int t = 0; t < 4; ++t) {
                float e = __expf(tv[t] - tm);
                l += e;
                w = fmaf(e, cst[t], w);
            }
            #pragma unroll
            for (int o = 8; o > 0; o >>= 1) {
                l += __shfl_xor(l, o, 16);
                w += __shfl_xor(w, o, 16);
            }
            if (cn == 0) {
                size_t o = (size_t)syb * (B_ * L_) + b * L_ + p0 + rbase + r;
                m_part[o] = tm;
                l_part[o] = l;
                w_part[o] = w;
            }
        }
    }
}

// ---------- K3: combine strips -> per-batch atomic sums; last block finalizes ----------
__global__ __launch_bounds__(256) void combine_kernel(
    const float* __restrict__ m_part, const float* __restrict__ l_part,
    const float* __restrict__ w_part,
    const float* __restrict__ x_mask, const float* __restrict__ y_mask,
    float* __restrict__ Sarr, unsigned int* __restrict__ counter,
    float* __restrict__ out) {
    int tid = threadIdx.x;
    int r = blockIdx.x * 256 + tid;  // 64 blocks, 8 per batch
    int b = r >> 11;
    float mm = -1e30f;
    #pragma unroll
    for (int s = 0; s < NSTRIP; ++s) mm = fmaxf(mm, m_part[(size_t)s * (B_ * L_) + r]);
    float l = 0.f, w = 0.f;
    #pragma unroll
    for (int s = 0; s < NSTRIP; ++s) {
        size_t o = (size_t)s * (B_ * L_) + r;
        float e = __expf(m_part[o] - mm);
        l = fmaf(l_part[o], e, l);
        w = fmaf(w_part[o], e, w);
    }
    float sv = w / l;
    float n1 = y_mask[r], n2 = x_mask[r];
    __shared__ float red[3][256];
    red[0][tid] = sv; red[1][tid] = n1; red[2][tid] = n2;
    __syncthreads();
    for (int o = 128; o > 0; o >>= 1) {
        if (tid < o) {
            red[0][tid] += red[0][tid + o];
            red[1][tid] += red[1][tid + o];
            red[2][tid] += red[2][tid + o];
        }
        __syncthreads();
    }
    __shared__ int isLast;
    if (tid == 0) {
        atomicAdd(&Sarr[b], red[0][0]);
        atomicAdd(&Sarr[8 + b], red[1][0]);
        atomicAdd(&Sarr[16 + b], red[2][0]);
        __threadfence();
        isLast = (atomicAdd(counter, 1u) == 63u) ? 1 : 0;
    }
    __syncthreads();
    if (isLast) {
        __shared__ float fb[24];
        if (tid < 24) fb[tid] = atomicAdd(&Sarr[tid], 0.f);  // coherent read
        __syncthreads();
        if (tid == 0) {
            float ss = 0.f, si = 0.f;
            for (int bb = 0; bb < B_; bb++) {
                ss += fb[bb];
                si += 1.0f / (fb[8 + bb] * fb[16 + bb]);
            }
            out[0] = ss * si / (float)(B_ * B_);  // LAMBDA_W = 1.0
        }
    }
}

extern "C" void kernel_launch(void* const* d_in, const int* in_sizes, int n_in,
                              void* d_out, int out_size, void* d_ws, size_t ws_size,
                              hipStream_t stream) {
    const float* h_x = (const float*)d_in[0];     // src
    const float* h_y = (const float*)d_in[1];     // pred
    const float* x_mask = (const float*)d_in[2];  // src_mask
    const float* y_mask = (const float*)d_in[3];  // pred_mask
    const float* W = (const float*)d_in[4];

    char* w8 = (char*)d_ws;
    const size_t BLD2 = (size_t)B_ * L_ * D_ * 2;  // 8 MB
    __bf16* srcFM = (__bf16*)w8;
    __bf16* predFM = (__bf16*)(w8 + BLD2);
    __bf16* pwFM = (__bf16*)(w8 + 2 * BLD2);
    __bf16* WFM = (__bf16*)(w8 + 3 * BLD2);                   // 128 KB
    float* src_sq = (float*)(w8 + 3 * BLD2 + (1 << 17));      // 64 KB
    float* pred_sq = (float*)(w8 + 3 * BLD2 + (1 << 17) + (1 << 16));
    char* pbase = w8 + 3 * BLD2 + (1 << 17) + (1 << 17);
    const size_t PSZ = (size_t)B_ * L_ * NSTRIP * 4;          // 2 MB each
    float* m_part = (float*)pbase;
    float* l_part = (float*)(pbase + PSZ);
    float* w_part = (float*)(pbase + 2 * PSZ);
    float* Sarr = (float*)(pbase + 3 * PSZ);                  // 24 floats
    unsigned int* counter = (unsigned int*)(pbase + 3 * PSZ + 128);

    convert_kernel<<<2080, 256, 0, stream>>>(h_x, h_y, W, srcFM, predFM, WFM,
                                             src_sq, pred_sq);
    predw_mfma<<<256, 256, 0, stream>>>(predFM, WFM, y_mask, pwFM);
    fused_mfma<<<4096, 256, 0, stream>>>(
        srcFM, predFM, pwFM, x_mask, y_mask, src_sq, pred_sq,
        m_part, l_part, w_part, Sarr, counter);
    combine_kernel<<<B_ * L_ / 256, 256, 0, stream>>>(
        m_part, l_part, w_part, x_mask, y_mask, Sarr, counter, (float*)d_out);
}